// Round 14
// baseline (770.916 us; speedup 1.0000x reference)
//
#include <hip/hip_runtime.h>
#include <hip/hip_bf16.h>

#define N_NODES 50000
#define N_EDGES 1600000
#define DIM 128
#define N_LAYERS 5
#define NEG 0.2f

#define NBKT 196          // dst >> 8
#define BCAP_A 9472       // arena cap per bucket (mean 8163)
#define PBLK 98           // partition blocks
#define EPB 16384         // edges per partition block
#define SEGCAP 12288      // k_scat staging entries (u16)

typedef unsigned short u16;
typedef unsigned char u8;
typedef unsigned int u32;
using short8 = __attribute__((ext_vector_type(8))) short;
using f32x4  = __attribute__((ext_vector_type(4))) float;

union FragU { uint4 u; short8 s; };

// ---------- helpers ----------
__device__ __forceinline__ float2 bf2x(u32 u) {
    union { u32 i; float f; } lo, hi;
    lo.i = u << 16;
    hi.i = u & 0xffff0000u;
    return make_float2(lo.f, hi.f);
}
__device__ __forceinline__ u16 f2bf(float f) {   // RNE
    union { float f; u32 u; } v; v.f = f;
    u32 r = v.u + 0x7fffu + ((v.u >> 16) & 1u);
    return (u16)(r >> 16);
}
__device__ __forceinline__ u32 pk2(float a, float b) {
    return (u32)f2bf(a) | ((u32)f2bf(b) << 16);
}
__device__ __forceinline__ int clampi(int v) {
    v = (v < 0) ? 0 : v;
    return (v >= N_NODES) ? (N_NODES - 1) : v;
}

// ---------- probe + bcnt zero ----------
__global__ void k_probe(const int* __restrict__ ei32, int* __restrict__ flags,
                        int* __restrict__ bcnt) {
    __shared__ int cnt;
    int t = threadIdx.x;
    if (t == 0) cnt = 0;
    __syncthreads();
    if (ei32[2 * t + 1] == 0) atomicAdd(&cnt, 1);
    if (t < NBKT) bcnt[t] = 0;
    __syncthreads();
    if (t == 0) flags[0] = (cnt >= 255) ? 1 : 0;
}

__device__ __forceinline__ int ldidx(const void* ei, long long i, int m64) {
    int v = m64 ? (int)(((const long long*)ei)[i]) : ((const int*)ei)[i];
    return clampi(v);
}

// ---------- conversions ----------
__global__ void k_cvt_x(const float* __restrict__ x, u16* __restrict__ xb) {
    int i = blockIdx.x * 256 + threadIdx.x;
    float2 v = *(const float2*)(x + (size_t)i * 2);
    ((u32*)xb)[i] = pk2(v.x, v.y);
}

__global__ void k_cvt_w(const float* __restrict__ Wl, const float* __restrict__ Wr,
                        uint4* __restrict__ Wtg) {
    int id = blockIdx.x * 256 + threadIdx.x;
    if (id >= N_LAYERS * 16 * 256) return;
    int l = id >> 12;
    int rem = id & 4095;
    int kc = rem >> 8;
    int n = rem & 255;
    const float* W = (n < 128) ? (Wl + (size_t)l * DIM * DIM + n)
                               : (Wr + (size_t)l * DIM * DIM + (n - 128));
    u16 c[8];
#pragma unroll
    for (int j = 0; j < 8; ++j) c[j] = f2bf(W[(size_t)(kc * 8 + j) * DIM]);
    uint4 o;
    o.x = (u32)c[0] | ((u32)c[1] << 16);
    o.y = (u32)c[2] | ((u32)c[3] << 16);
    o.z = (u32)c[4] | ((u32)c[5] << 16);
    o.w = (u32)c[6] | ((u32)c[7] << 16);
    Wtg[(size_t)l * 4096 + n * 16 + (kc ^ (n & 15))] = o;
}

// ---------- CSR build: LDS-staged bucket partition ----------
__global__ __launch_bounds__(1024) void k_part(
    const void* __restrict__ ei, const int* __restrict__ flags,
    int* __restrict__ bcnt, u32* __restrict__ bpk)
{
    __shared__ u32 ebuf[EPB];        // 64 KB
    __shared__ u8  bkb[EPB];         // 16 KB
    __shared__ int lh[NBKT];
    __shared__ int lb[NBKT + 1];
    __shared__ int gst[NBKT];
    __shared__ int sc[256];

    const int tid = threadIdx.x;
    const int m64 = flags[0];
    const long long e0 = (long long)blockIdx.x * EPB;

    for (int i = tid; i < NBKT; i += 1024) lh[i] = 0;
    __syncthreads();

    u32 pay[16];
    u32 meta[16];
    int nv = 0;
#pragma unroll
    for (int i = 0; i < 16; ++i) {
        long long e = e0 + i * 1024 + tid;
        if (e < N_EDGES) {
            int s = ldidx(ei, e, m64);
            int d = ldidx(ei, (long long)N_EDGES + e, m64);
            int b = d >> 8;
            int rank = atomicAdd(&lh[b], 1);
            pay[i] = (u32)s | ((u32)(d & 255) << 16);
            meta[i] = (u32)b | ((u32)rank << 8);
            nv = i + 1;
        }
    }
    __syncthreads();

    if (tid < 256) sc[tid] = (tid < NBKT) ? lh[tid] : 0;
    __syncthreads();
    for (int off = 1; off < 256; off <<= 1) {
        int v = 0;
        if (tid < 256 && tid >= off) v = sc[tid - off];
        __syncthreads();
        if (tid < 256) sc[tid] += v;
        __syncthreads();
    }
    if (tid < NBKT) lb[tid] = sc[tid] - lh[tid];
    if (tid == 0) lb[NBKT] = 0;
    if (tid < NBKT) gst[tid] = atomicAdd(&bcnt[tid], lh[tid]);
    __syncthreads();

#pragma unroll
    for (int i = 0; i < 16; ++i) {
        if (i < nv) {
            int b = (int)(meta[i] & 255);
            int rank = (int)(meta[i] >> 8);
            int p = lb[b] + rank;
            ebuf[p] = pay[i];
            bkb[p] = (u8)b;
        }
    }
    __syncthreads();

    int total = (e0 + EPB <= N_EDGES) ? EPB : (int)(N_EDGES - e0);
    for (int i = tid; i < total; i += 1024) {
        int b = (int)bkb[i];
        int off = gst[b] + (i - lb[b]);
        if (off < BCAP_A)
            bpk[(size_t)b * BCAP_A + off] = ebuf[i];
    }
}

// per-bucket degree + LOCAL row_off scan + bucket total
__global__ __launch_bounds__(256) void k_deg(
    const u32* __restrict__ bpk, const int* __restrict__ bcnt,
    const void* __restrict__ ei, const int* __restrict__ flags,
    int* __restrict__ row_off, int* __restrict__ btot)
{
    __shared__ int dh[256];
    __shared__ int sc[256];
    int b = blockIdx.x;
    int tid = threadIdx.x;
    dh[tid] = 0;
    __syncthreads();
    int cnt = bcnt[b];
    if (cnt <= BCAP_A) {
        for (int i = tid; i < cnt; i += 256)
            atomicAdd(&dh[(bpk[(size_t)b * BCAP_A + i] >> 16) & 255], 1);
    } else {
        int m64 = flags[0];
        for (long long e = tid; e < N_EDGES; e += 256) {
            int d = ldidx(ei, (long long)N_EDGES + e, m64);
            if ((d >> 8) == b) atomicAdd(&dh[d & 255], 1);
        }
    }
    __syncthreads();
    int d = b * 256 + tid;
    int v = (d < N_NODES) ? (dh[tid] + 1) : 0;    // +1 self loop
    sc[tid] = v;
    __syncthreads();
    for (int off = 1; off < 256; off <<= 1) {
        int t = (tid >= off) ? sc[tid - off] : 0;
        __syncthreads();
        sc[tid] += t;
        __syncthreads();
    }
    if (d < N_NODES) row_off[d] = sc[tid] - v;    // local exclusive
    if (tid == 255) btot[b] = sc[255];
}

__global__ void k_bscan(const int* __restrict__ btot, int* __restrict__ boff,
                        int* __restrict__ row_off) {
    __shared__ int sc[256];
    int tid = threadIdx.x;
    int v = (tid < NBKT) ? btot[tid] : 0;
    sc[tid] = v;
    __syncthreads();
    for (int off = 1; off < 256; off <<= 1) {
        int t = (tid >= off) ? sc[tid - off] : 0;
        __syncthreads();
        sc[tid] += t;
        __syncthreads();
    }
    if (tid < NBKT) boff[tid] = sc[tid] - v;
    if (tid == NBKT - 1) row_off[N_NODES] = sc[tid];
}

__global__ __launch_bounds__(256) void k_scat(
    const u32* __restrict__ bpk, const int* __restrict__ bcnt,
    int* __restrict__ row_off, const int* __restrict__ boff,
    const int* __restrict__ btot, u16* __restrict__ col,
    const void* __restrict__ ei, const int* __restrict__ flags)
{
    __shared__ u16 stage[SEGCAP];    // 24 KB
    __shared__ int cur[256];
    int b = blockIdx.x;
    int tid = threadIdx.x;
    int d_lo = b * 256;
    int d_hi = d_lo + 256; if (d_hi > N_NODES) d_hi = N_NODES;
    int base0 = boff[b];
    int seglen = btot[b];
    if (seglen > SEGCAP) seglen = SEGCAP;

    int d = d_lo + tid;
    int rloc = 0;
    if (d < d_hi) {
        rloc = row_off[d];
        if (rloc < SEGCAP) stage[rloc] = (u16)d;
        cur[tid] = rloc + 1;
    }
    __syncthreads();

    int cnt = bcnt[b];
    if (cnt <= BCAP_A) {
        for (int i = tid; i < cnt; i += 256) {
            u32 p = bpk[(size_t)b * BCAP_A + i];
            int pos = atomicAdd(&cur[(p >> 16) & 255], 1);
            if (pos < SEGCAP) stage[pos] = (u16)(p & 0xffff);
        }
    } else {
        int m64 = flags[0];
        for (long long e = tid; e < N_EDGES; e += 256) {
            int dd = ldidx(ei, (long long)N_EDGES + e, m64);
            if ((dd >> 8) == b) {
                int s = ldidx(ei, e, m64);
                int pos = atomicAdd(&cur[dd & 255], 1);
                if (pos < SEGCAP) stage[pos] = (u16)s;
            }
        }
    }
    __syncthreads();
    for (int i = tid; i < seglen; i += 256)
        col[base0 + i] = stage[i];
    if (d < d_hi) row_off[d] = base0 + rloc;
}

// ---------- MFMA GEMM + fused als GEMV epilogue ----------
// als[m] = 0.6 * att . xl[m]  (xl incl. bias); xr stored bf16.
__global__ __launch_bounds__(256) void k_mm(
    const u16* __restrict__ hb,
    const uint4* __restrict__ Wtg,
    const float* __restrict__ bl, const float* __restrict__ br,
    const float* __restrict__ att,
    u16* __restrict__ xlb,
    u16* __restrict__ xrb,
    float* __restrict__ als)
{
    __shared__ uint4 wsh[4096];          // 64 KB
    const int tid = threadIdx.x;
#pragma unroll
    for (int i = 0; i < 16; ++i) wsh[tid + i * 256] = Wtg[tid + i * 256];

    const int wave = tid >> 6, lane = tid & 63;
    const int q = lane >> 4, nn = lane & 15;
    const int mA = blockIdx.x * 64 + wave * 16 + nn;

    FragU afr[4];
    const uint4 az = make_uint4(0, 0, 0, 0);
#pragma unroll
    for (int s = 0; s < 4; ++s)
        afr[s].u = (mA < N_NODES)
                 ? *(const uint4*)(hb + (size_t)mA * DIM + s * 32 + q * 8)
                 : az;
    __syncthreads();

    f32x4 acc[16];
#pragma unroll
    for (int i = 0; i < 16; ++i) acc[i] = (f32x4){0.f, 0.f, 0.f, 0.f};

#pragma unroll
    for (int s = 0; s < 4; ++s) {
#pragma unroll
        for (int nt = 0; nt < 16; ++nt) {
            int n = nt * 16 + nn;
            int kc = s * 4 + q;
            FragU b;
            b.u = wsh[n * 16 + (kc ^ (n & 15))];
            acc[nt] = __builtin_amdgcn_mfma_f32_16x16x32_bf16(afr[s].s, b.s, acc[nt], 0, 0, 0);
        }
    }

    float attw[8];
#pragma unroll
    for (int nt = 0; nt < 8; ++nt) attw[nt] = att[nt * 16 + nn];
    float alp[4] = {0.f, 0.f, 0.f, 0.f};

    const int mBase = blockIdx.x * 64 + wave * 16 + q * 4;
#pragma unroll
    for (int nt = 0; nt < 16; ++nt) {
        int n = nt * 16 + nn;
        bool isL = (n < 128);
        float bv = isL ? bl[n] : br[n - 128];
#pragma unroll
        for (int r = 0; r < 4; ++r) {
            int m = mBase + r;
            if (m < N_NODES) {
                float v = acc[nt][r] + bv;
                if (isL) {
                    xlb[(size_t)m * DIM + n] = f2bf(v);
                    alp[r] = fmaf(attw[nt], v, alp[r]);
                } else {
                    xrb[(size_t)m * DIM + (n - 128)] = f2bf(v);
                }
            }
        }
    }
    // reduce alp across the 16 nn lanes (same rows)
#pragma unroll
    for (int r = 0; r < 4; ++r) {
        float s = alp[r];
        s += __shfl_xor(s, 1, 64);
        s += __shfl_xor(s, 2, 64);
        s += __shfl_xor(s, 4, 64);
        s += __shfl_xor(s, 8, 64);
        int m = mBase + r;
        if (nn == 0 && m < N_NODES) als[m] = 0.6f * s;
    }
}

// ---------- fused edge phase: |z| decomposition + register col + volleys ----------
// score' = 0.4*att.|z| + 0.6*att.xl[s]  (0.6*att.xr[d] cancels in softmax)
template <int RELU>
__global__ __launch_bounds__(256) void k_edge(
    const u16* __restrict__ xlb, const u16* __restrict__ xrb,
    const float* __restrict__ als,
    const int* __restrict__ row_off, const u16* __restrict__ col,
    const float* __restrict__ att, const float* __restrict__ bias,
    u16* __restrict__ hout)
{
    int gtid = blockIdx.x * 256 + threadIdx.x;
    int node = gtid >> 6;
    int lane = threadIdx.x & 63;
    int g = lane >> 4;
    int t = lane & 15;
    if (node >= N_NODES) return;

    const int d0 = t * 8;
    uint4 xru = *(const uint4*)(xrb + (size_t)node * DIM + d0);
    float2 q0 = bf2x(xru.x), q1 = bf2x(xru.y), q2 = bf2x(xru.z), q3 = bf2x(xru.w);
    float4 xr0 = make_float4(q0.x, q0.y, q1.x, q1.y);
    float4 xr1 = make_float4(q2.x, q2.y, q3.x, q3.y);
    float4 at0 = *(const float4*)(att + d0);
    float4 at1 = *(const float4*)(att + d0 + 4);
    at0.x *= 0.4f; at0.y *= 0.4f; at0.z *= 0.4f; at0.w *= 0.4f;
    at1.x *= 0.4f; at1.y *= 0.4f; at1.z *= 0.4f; at1.w *= 0.4f;

    const int beg = row_off[node];
    const int end = row_off[node + 1];
    const int n = end - beg;
    const int nreg = (n < 64) ? n : 64;

    int idx = (lane < nreg) ? (int)col[beg + lane] : 0;
    float alv = (lane < nreg) ? als[idx] : 0.f;

    float acc[8];
#pragma unroll
    for (int i = 0; i < 8; ++i) acc[i] = 0.f;
    float lsum = 0.f;

    const u16* basep = xlb + d0;

#pragma unroll 1
    for (int k0 = 0; k0 < 16; k0 += 8) {
        uint4 u[8];
#pragma unroll
        for (int k = 0; k < 8; ++k) {
            int p = g + 4 * (k0 + k);
            int ps = (p < nreg) ? p : 0;
            int s = __shfl(idx, ps, 64);
            if (p < nreg)
                u[k] = *(const uint4*)(basep + (size_t)s * DIM);
        }
#pragma unroll
        for (int k = 0; k < 8; ++k) {
            int p = g + 4 * (k0 + k);
            if (p < nreg) {
                float2 p0 = bf2x(u[k].x), p1 = bf2x(u[k].y), p2 = bf2x(u[k].z), p3 = bf2x(u[k].w);
                float v0 = p0.x + xr0.x, v1 = p0.y + xr0.y, v2 = p1.x + xr0.z, v3 = p1.y + xr0.w;
                float v4 = p2.x + xr1.x, v5 = p2.y + xr1.y, v6 = p3.x + xr1.z, v7 = p3.y + xr1.w;
                float pp = at0.x * __builtin_fabsf(v0);
                pp = fmaf(at0.y, __builtin_fabsf(v1), pp);
                pp = fmaf(at0.z, __builtin_fabsf(v2), pp);
                pp = fmaf(at0.w, __builtin_fabsf(v3), pp);
                pp = fmaf(at1.x, __builtin_fabsf(v4), pp);
                pp = fmaf(at1.y, __builtin_fabsf(v5), pp);
                pp = fmaf(at1.z, __builtin_fabsf(v6), pp);
                pp = fmaf(at1.w, __builtin_fabsf(v7), pp);
                pp += __shfl_xor(pp, 1, 64);
                pp += __shfl_xor(pp, 2, 64);
                pp += __shfl_xor(pp, 4, 64);
                pp += __shfl_xor(pp, 8, 64);
                float alj = __shfl(alv, p, 64);
                float w = __expf(pp + alj);
                lsum += w;
                acc[0] = fmaf(w, p0.x, acc[0]);
                acc[1] = fmaf(w, p0.y, acc[1]);
                acc[2] = fmaf(w, p1.x, acc[2]);
                acc[3] = fmaf(w, p1.y, acc[3]);
                acc[4] = fmaf(w, p2.x, acc[4]);
                acc[5] = fmaf(w, p2.y, acc[5]);
                acc[6] = fmaf(w, p3.x, acc[6]);
                acc[7] = fmaf(w, p3.y, acc[7]);
            }
        }
    }

    // rare tail: rows longer than 64
    for (int j = beg + 64 + g; j < end; j += 4) {
        int s = (int)col[j];
        uint4 u = *(const uint4*)(basep + (size_t)s * DIM);
        float2 p0 = bf2x(u.x), p1 = bf2x(u.y), p2 = bf2x(u.z), p3 = bf2x(u.w);
        float v0 = p0.x + xr0.x, v1 = p0.y + xr0.y, v2 = p1.x + xr0.z, v3 = p1.y + xr0.w;
        float v4 = p2.x + xr1.x, v5 = p2.y + xr1.y, v6 = p3.x + xr1.z, v7 = p3.y + xr1.w;
        float pp = at0.x * __builtin_fabsf(v0);
        pp = fmaf(at0.y, __builtin_fabsf(v1), pp);
        pp = fmaf(at0.z, __builtin_fabsf(v2), pp);
        pp = fmaf(at0.w, __builtin_fabsf(v3), pp);
        pp = fmaf(at1.x, __builtin_fabsf(v4), pp);
        pp = fmaf(at1.y, __builtin_fabsf(v5), pp);
        pp = fmaf(at1.z, __builtin_fabsf(v6), pp);
        pp = fmaf(at1.w, __builtin_fabsf(v7), pp);
        pp += __shfl_xor(pp, 1, 64);
        pp += __shfl_xor(pp, 2, 64);
        pp += __shfl_xor(pp, 4, 64);
        pp += __shfl_xor(pp, 8, 64);
        float w = __expf(pp + als[s]);
        lsum += w;
        acc[0] = fmaf(w, p0.x, acc[0]);
        acc[1] = fmaf(w, p0.y, acc[1]);
        acc[2] = fmaf(w, p1.x, acc[2]);
        acc[3] = fmaf(w, p1.y, acc[3]);
        acc[4] = fmaf(w, p2.x, acc[4]);
        acc[5] = fmaf(w, p2.y, acc[5]);
        acc[6] = fmaf(w, p3.x, acc[6]);
        acc[7] = fmaf(w, p3.y, acc[7]);
    }

#pragma unroll
    for (int i = 0; i < 8; ++i) {
        acc[i] += __shfl_xor(acc[i], 16, 64);
        acc[i] += __shfl_xor(acc[i], 32, 64);
    }
    lsum += __shfl_xor(lsum, 16, 64);
    lsum += __shfl_xor(lsum, 32, 64);

    if (g == 0) {
        float inv = 1.f / fmaxf(lsum, 1e-16f);
        float4 b0 = *(const float4*)(bias + d0);
        float4 b1 = *(const float4*)(bias + d0 + 4);
        float o0 = acc[0] * inv + b0.x;
        float o1 = acc[1] * inv + b0.y;
        float o2 = acc[2] * inv + b0.z;
        float o3 = acc[3] * inv + b0.w;
        float o4 = acc[4] * inv + b1.x;
        float o5 = acc[5] * inv + b1.y;
        float o6 = acc[6] * inv + b1.z;
        float o7 = acc[7] * inv + b1.w;
        if (RELU) {
            o0 = fmaxf(o0, 0.f); o1 = fmaxf(o1, 0.f);
            o2 = fmaxf(o2, 0.f); o3 = fmaxf(o3, 0.f);
            o4 = fmaxf(o4, 0.f); o5 = fmaxf(o5, 0.f);
            o6 = fmaxf(o6, 0.f); o7 = fmaxf(o7, 0.f);
        }
        uint4 o;
        o.x = pk2(o0, o1);
        o.y = pk2(o2, o3);
        o.z = pk2(o4, o5);
        o.w = pk2(o6, o7);
        *(uint4*)(hout + (size_t)node * DIM + d0) = o;
    }
}

// ---------- mean pool (bf16 h) ----------
__global__ void k_mean_part(const u16* __restrict__ hb, float* __restrict__ part) {
    int d = threadIdx.x;
    int b = blockIdx.x;
    int n0 = b * 200;
    float s = 0.f;
    for (int i = 0; i < 200; ++i) {
        union { u32 i; float f; } v;
        v.i = (u32)hb[(size_t)(n0 + i) * DIM + d] << 16;
        s += v.f;
    }
    part[b * DIM + d] = s;
}

__global__ void k_mean_final(const float* __restrict__ part, float* __restrict__ out) {
    int d = threadIdx.x;
    float s = 0.f;
    for (int b = 0; b < 250; ++b) s += part[b * DIM + d];
    out[d] = s * (1.f / (float)N_NODES);
}

// ---------- launch ----------
extern "C" void kernel_launch(void* const* d_in, const int* in_sizes, int n_in,
                              void* d_out, int out_size, void* d_ws, size_t ws_size,
                              hipStream_t stream) {
    int ix, iei, iWl, ibl, iWr, ibr, iatt, ibias;
    if (in_sizes[0] == N_NODES * DIM) {
        ix = 0; iei = 1; iWl = 2; ibl = 3; iWr = 4; ibr = 5; iatt = 6; ibias = 7;
    } else {
        iWl = 0; iWr = 1; iatt = 2; ibias = 3; ibl = 4; ibr = 5; iei = 6; ix = 7;
    }
    const float* x    = (const float*)d_in[ix];
    const void*  ei   = d_in[iei];
    const float* Wl   = (const float*)d_in[iWl];
    const float* bl   = (const float*)d_in[ibl];
    const float* Wr   = (const float*)d_in[iWr];
    const float* br   = (const float*)d_in[ibr];
    const float* att  = (const float*)d_in[iatt];
    const float* bias = (const float*)d_in[ibias];
    float* out = (float*)d_out;

    char* w = (char*)d_ws;
    float* part = (float*)w;      w += (size_t)256 * DIM * 4;
    float* als = (float*)w;       w += (size_t)(N_NODES + 16) * 4;
    uint4* Wtg = (uint4*)w;       w += (size_t)N_LAYERS * 4096 * 16;
    u16* xb  = (u16*)w;           w += (size_t)N_NODES * DIM * 2;
    u16* hb  = (u16*)w;           w += (size_t)N_NODES * DIM * 2;
    u16* xlb = (u16*)w;           w += (size_t)N_NODES * DIM * 2;
    u16* xrb = (u16*)w;           w += (size_t)N_NODES * DIM * 2;
    int* row_off = (int*)w;       w += (size_t)(N_NODES + 4) * 4;
    int* flags = (int*)w;         w += 64;
    int* bcnt = (int*)w;          w += (size_t)(NBKT + 4) * 4;
    int* btot = (int*)w;          w += (size_t)(NBKT + 4) * 4;
    int* boff = (int*)w;          w += (size_t)(NBKT + 4) * 4;
    u32* bpk = (u32*)w;           w += (size_t)NBKT * BCAP_A * 4;
    u16* col = (u16*)w;           w += (size_t)(N_EDGES + N_NODES + 64) * 2;

    k_probe<<<1, 256, 0, stream>>>((const int*)ei, flags, bcnt);
    k_cvt_x<<<(N_NODES * DIM / 2 + 255) / 256, 256, 0, stream>>>(x, xb);
    k_cvt_w<<<(N_LAYERS * 4096 + 255) / 256, 256, 0, stream>>>(Wl, Wr, Wtg);
    k_part<<<PBLK, 1024, 0, stream>>>(ei, flags, bcnt, bpk);
    k_deg<<<NBKT, 256, 0, stream>>>(bpk, bcnt, ei, flags, row_off, btot);
    k_bscan<<<1, 256, 0, stream>>>(btot, boff, row_off);
    k_scat<<<NBKT, 256, 0, stream>>>(bpk, bcnt, row_off, boff, btot, col, ei, flags);

    const int mm_grid = (N_NODES + 63) / 64;
    const int edge_grid = (N_NODES * 64 + 255) / 256;

    for (int layer = 0; layer < N_LAYERS; ++layer) {
        const uint4* Wp = Wtg + (size_t)layer * 4096;
        const float* blp = bl + (size_t)layer * DIM;
        const float* brp = br + (size_t)layer * DIM;
        const float* ap  = att + (size_t)layer * DIM;
        const float* bp  = bias + (size_t)layer * DIM;

        const u16* hin = (layer == 0) ? xb : hb;
        k_mm<<<mm_grid, 256, 0, stream>>>(hin, Wp, blp, brp, ap, xlb, xrb, als);

        if (layer < N_LAYERS - 1)
            k_edge<1><<<edge_grid, 256, 0, stream>>>(xlb, xrb, als, row_off, col, ap, bp, hb);
        else
            k_edge<0><<<edge_grid, 256, 0, stream>>>(xlb, xrb, als, row_off, col, ap, bp, hb);
    }

    k_mean_part<<<250, 128, 0, stream>>>(hb, part);
    k_mean_final<<<1, 128, 0, stream>>>(part, out);
}

// Round 15
// 714.908 us; speedup vs baseline: 1.0783x; 1.0783x over previous
//
#include <hip/hip_runtime.h>
#include <hip/hip_bf16.h>

#define N_NODES 50000
#define N_EDGES 1600000
#define DIM 128
#define N_LAYERS 5
#define NEG 0.2f

#define NBKT 196          // dst >> 8
#define BCAP_A 9472       // arena cap per bucket (mean 8163)
#define PBLK 98           // partition blocks
#define EPB 16384         // edges per partition block
#define SEGCAP 12288      // k_scat staging entries (u16)

typedef unsigned short u16;
typedef unsigned char u8;
typedef unsigned int u32;
using short8 = __attribute__((ext_vector_type(8))) short;
using f32x4  = __attribute__((ext_vector_type(4))) float;

union FragU { uint4 u; short8 s; };

// ---------- helpers ----------
__device__ __forceinline__ float2 bf2x(u32 u) {
    union { u32 i; float f; } lo, hi;
    lo.i = u << 16;
    hi.i = u & 0xffff0000u;
    return make_float2(lo.f, hi.f);
}
__device__ __forceinline__ float bf1(u32 hi16) {   // decode bf16 stored in low 16 bits
    union { u32 i; float f; } v;
    v.i = hi16 << 16;
    return v.f;
}
__device__ __forceinline__ u16 f2bf(float f) {   // RNE
    union { float f; u32 u; } v; v.f = f;
    u32 r = v.u + 0x7fffu + ((v.u >> 16) & 1u);
    return (u16)(r >> 16);
}
__device__ __forceinline__ u32 pk2(float a, float b) {
    return (u32)f2bf(a) | ((u32)f2bf(b) << 16);
}
__device__ __forceinline__ int clampi(int v) {
    v = (v < 0) ? 0 : v;
    return (v >= N_NODES) ? (N_NODES - 1) : v;
}

// ---------- probe + bcnt zero ----------
__global__ void k_probe(const int* __restrict__ ei32, int* __restrict__ flags,
                        int* __restrict__ bcnt) {
    __shared__ int cnt;
    int t = threadIdx.x;
    if (t == 0) cnt = 0;
    __syncthreads();
    if (ei32[2 * t + 1] == 0) atomicAdd(&cnt, 1);
    if (t < NBKT) bcnt[t] = 0;
    __syncthreads();
    if (t == 0) flags[0] = (cnt >= 255) ? 1 : 0;
}

__device__ __forceinline__ int ldidx(const void* ei, long long i, int m64) {
    int v = m64 ? (int)(((const long long*)ei)[i]) : ((const int*)ei)[i];
    return clampi(v);
}

// ---------- conversions ----------
__global__ void k_cvt_x(const float* __restrict__ x, u16* __restrict__ xb) {
    int i = blockIdx.x * 256 + threadIdx.x;
    float2 v = *(const float2*)(x + (size_t)i * 2);
    ((u32*)xb)[i] = pk2(v.x, v.y);
}

__global__ void k_cvt_w(const float* __restrict__ Wl, const float* __restrict__ Wr,
                        uint4* __restrict__ Wtg) {
    int id = blockIdx.x * 256 + threadIdx.x;
    if (id >= N_LAYERS * 16 * 256) return;
    int l = id >> 12;
    int rem = id & 4095;
    int kc = rem >> 8;
    int n = rem & 255;
    const float* W = (n < 128) ? (Wl + (size_t)l * DIM * DIM + n)
                               : (Wr + (size_t)l * DIM * DIM + (n - 128));
    u16 c[8];
#pragma unroll
    for (int j = 0; j < 8; ++j) c[j] = f2bf(W[(size_t)(kc * 8 + j) * DIM]);
    uint4 o;
    o.x = (u32)c[0] | ((u32)c[1] << 16);
    o.y = (u32)c[2] | ((u32)c[3] << 16);
    o.z = (u32)c[4] | ((u32)c[5] << 16);
    o.w = (u32)c[6] | ((u32)c[7] << 16);
    Wtg[(size_t)l * 4096 + n * 16 + (kc ^ (n & 15))] = o;
}

// ---------- CSR build: LDS-staged bucket partition ----------
__global__ __launch_bounds__(1024) void k_part(
    const void* __restrict__ ei, const int* __restrict__ flags,
    int* __restrict__ bcnt, u32* __restrict__ bpk)
{
    __shared__ u32 ebuf[EPB];        // 64 KB
    __shared__ u8  bkb[EPB];         // 16 KB
    __shared__ int lh[NBKT];
    __shared__ int lb[NBKT + 1];
    __shared__ int gst[NBKT];
    __shared__ int sc[256];

    const int tid = threadIdx.x;
    const int m64 = flags[0];
    const long long e0 = (long long)blockIdx.x * EPB;

    for (int i = tid; i < NBKT; i += 1024) lh[i] = 0;
    __syncthreads();

    u32 pay[16];
    u32 meta[16];
    int nv = 0;
#pragma unroll
    for (int i = 0; i < 16; ++i) {
        long long e = e0 + i * 1024 + tid;
        if (e < N_EDGES) {
            int s = ldidx(ei, e, m64);
            int d = ldidx(ei, (long long)N_EDGES + e, m64);
            int b = d >> 8;
            int rank = atomicAdd(&lh[b], 1);
            pay[i] = (u32)s | ((u32)(d & 255) << 16);
            meta[i] = (u32)b | ((u32)rank << 8);
            nv = i + 1;
        }
    }
    __syncthreads();

    if (tid < 256) sc[tid] = (tid < NBKT) ? lh[tid] : 0;
    __syncthreads();
    for (int off = 1; off < 256; off <<= 1) {
        int v = 0;
        if (tid < 256 && tid >= off) v = sc[tid - off];
        __syncthreads();
        if (tid < 256) sc[tid] += v;
        __syncthreads();
    }
    if (tid < NBKT) lb[tid] = sc[tid] - lh[tid];
    if (tid == 0) lb[NBKT] = 0;
    if (tid < NBKT) gst[tid] = atomicAdd(&bcnt[tid], lh[tid]);
    __syncthreads();

#pragma unroll
    for (int i = 0; i < 16; ++i) {
        if (i < nv) {
            int b = (int)(meta[i] & 255);
            int rank = (int)(meta[i] >> 8);
            int p = lb[b] + rank;
            ebuf[p] = pay[i];
            bkb[p] = (u8)b;
        }
    }
    __syncthreads();

    int total = (e0 + EPB <= N_EDGES) ? EPB : (int)(N_EDGES - e0);
    for (int i = tid; i < total; i += 1024) {
        int b = (int)bkb[i];
        int off = gst[b] + (i - lb[b]);
        if (off < BCAP_A)
            bpk[(size_t)b * BCAP_A + off] = ebuf[i];
    }
}

// per-bucket degree + LOCAL row_off scan + bucket total
__global__ __launch_bounds__(256) void k_deg(
    const u32* __restrict__ bpk, const int* __restrict__ bcnt,
    const void* __restrict__ ei, const int* __restrict__ flags,
    int* __restrict__ row_off, int* __restrict__ btot)
{
    __shared__ int dh[256];
    __shared__ int sc[256];
    int b = blockIdx.x;
    int tid = threadIdx.x;
    dh[tid] = 0;
    __syncthreads();
    int cnt = bcnt[b];
    if (cnt <= BCAP_A) {
        for (int i = tid; i < cnt; i += 256)
            atomicAdd(&dh[(bpk[(size_t)b * BCAP_A + i] >> 16) & 255], 1);
    } else {
        int m64 = flags[0];
        for (long long e = tid; e < N_EDGES; e += 256) {
            int d = ldidx(ei, (long long)N_EDGES + e, m64);
            if ((d >> 8) == b) atomicAdd(&dh[d & 255], 1);
        }
    }
    __syncthreads();
    int d = b * 256 + tid;
    int v = (d < N_NODES) ? (dh[tid] + 1) : 0;    // +1 self loop
    sc[tid] = v;
    __syncthreads();
    for (int off = 1; off < 256; off <<= 1) {
        int t = (tid >= off) ? sc[tid - off] : 0;
        __syncthreads();
        sc[tid] += t;
        __syncthreads();
    }
    if (d < N_NODES) row_off[d] = sc[tid] - v;    // local exclusive
    if (tid == 255) btot[b] = sc[255];
}

__global__ void k_bscan(const int* __restrict__ btot, int* __restrict__ boff,
                        int* __restrict__ row_off) {
    __shared__ int sc[256];
    int tid = threadIdx.x;
    int v = (tid < NBKT) ? btot[tid] : 0;
    sc[tid] = v;
    __syncthreads();
    for (int off = 1; off < 256; off <<= 1) {
        int t = (tid >= off) ? sc[tid - off] : 0;
        __syncthreads();
        sc[tid] += t;
        __syncthreads();
    }
    if (tid < NBKT) boff[tid] = sc[tid] - v;
    if (tid == NBKT - 1) row_off[N_NODES] = sc[tid];
}

__global__ __launch_bounds__(256) void k_scat(
    const u32* __restrict__ bpk, const int* __restrict__ bcnt,
    int* __restrict__ row_off, const int* __restrict__ boff,
    const int* __restrict__ btot, u16* __restrict__ col,
    const void* __restrict__ ei, const int* __restrict__ flags)
{
    __shared__ u16 stage[SEGCAP];    // 24 KB
    __shared__ int cur[256];
    int b = blockIdx.x;
    int tid = threadIdx.x;
    int d_lo = b * 256;
    int d_hi = d_lo + 256; if (d_hi > N_NODES) d_hi = N_NODES;
    int base0 = boff[b];
    int seglen = btot[b];
    if (seglen > SEGCAP) seglen = SEGCAP;

    int d = d_lo + tid;
    int rloc = 0;
    if (d < d_hi) {
        rloc = row_off[d];
        if (rloc < SEGCAP) stage[rloc] = (u16)d;
        cur[tid] = rloc + 1;
    }
    __syncthreads();

    int cnt = bcnt[b];
    if (cnt <= BCAP_A) {
        for (int i = tid; i < cnt; i += 256) {
            u32 p = bpk[(size_t)b * BCAP_A + i];
            int pos = atomicAdd(&cur[(p >> 16) & 255], 1);
            if (pos < SEGCAP) stage[pos] = (u16)(p & 0xffff);
        }
    } else {
        int m64 = flags[0];
        for (long long e = tid; e < N_EDGES; e += 256) {
            int dd = ldidx(ei, (long long)N_EDGES + e, m64);
            if ((dd >> 8) == b) {
                int s = ldidx(ei, e, m64);
                int pos = atomicAdd(&cur[dd & 255], 1);
                if (pos < SEGCAP) stage[pos] = (u16)s;
            }
        }
    }
    __syncthreads();
    for (int i = tid; i < seglen; i += 256)
        col[base0 + i] = stage[i];
    if (d < d_hi) row_off[d] = base0 + rloc;
}

// ---------- MFMA GEMM + fused als GEMV epilogue ----------
// als[m] = bf16( 0.6 * att . xl[m] ); xl, xr stored bf16.
__global__ __launch_bounds__(256) void k_mm(
    const u16* __restrict__ hb,
    const uint4* __restrict__ Wtg,
    const float* __restrict__ bl, const float* __restrict__ br,
    const float* __restrict__ att,
    u16* __restrict__ xlb,
    u16* __restrict__ xrb,
    u16* __restrict__ als)
{
    __shared__ uint4 wsh[4096];          // 64 KB
    const int tid = threadIdx.x;
#pragma unroll
    for (int i = 0; i < 16; ++i) wsh[tid + i * 256] = Wtg[tid + i * 256];

    const int wave = tid >> 6, lane = tid & 63;
    const int q = lane >> 4, nn = lane & 15;
    const int mA = blockIdx.x * 64 + wave * 16 + nn;

    FragU afr[4];
    const uint4 az = make_uint4(0, 0, 0, 0);
#pragma unroll
    for (int s = 0; s < 4; ++s)
        afr[s].u = (mA < N_NODES)
                 ? *(const uint4*)(hb + (size_t)mA * DIM + s * 32 + q * 8)
                 : az;
    __syncthreads();

    f32x4 acc[16];
#pragma unroll
    for (int i = 0; i < 16; ++i) acc[i] = (f32x4){0.f, 0.f, 0.f, 0.f};

#pragma unroll
    for (int s = 0; s < 4; ++s) {
#pragma unroll
        for (int nt = 0; nt < 16; ++nt) {
            int n = nt * 16 + nn;
            int kc = s * 4 + q;
            FragU b;
            b.u = wsh[n * 16 + (kc ^ (n & 15))];
            acc[nt] = __builtin_amdgcn_mfma_f32_16x16x32_bf16(afr[s].s, b.s, acc[nt], 0, 0, 0);
        }
    }

    float attw[8];
#pragma unroll
    for (int nt = 0; nt < 8; ++nt) attw[nt] = att[nt * 16 + nn];
    float alp[4] = {0.f, 0.f, 0.f, 0.f};

    const int mBase = blockIdx.x * 64 + wave * 16 + q * 4;
#pragma unroll
    for (int nt = 0; nt < 16; ++nt) {
        int n = nt * 16 + nn;
        bool isL = (n < 128);
        float bv = isL ? bl[n] : br[n - 128];
#pragma unroll
        for (int r = 0; r < 4; ++r) {
            int m = mBase + r;
            if (m < N_NODES) {
                float v = acc[nt][r] + bv;
                if (isL) {
                    xlb[(size_t)m * DIM + n] = f2bf(v);
                    alp[r] = fmaf(attw[nt], v, alp[r]);
                } else {
                    xrb[(size_t)m * DIM + (n - 128)] = f2bf(v);
                }
            }
        }
    }
#pragma unroll
    for (int r = 0; r < 4; ++r) {
        float s = alp[r];
        s += __shfl_xor(s, 1, 64);
        s += __shfl_xor(s, 2, 64);
        s += __shfl_xor(s, 4, 64);
        s += __shfl_xor(s, 8, 64);
        int m = mBase + r;
        if (nn == 0 && m < N_NODES) als[m] = f2bf(0.6f * s);
    }
}

// ---------- fused edge phase: |z| decomposition, single-bpermute chain ----------
// score' = 0.4*att.|z| + 0.6*att.xl[s]; idx & als packed in ONE u32 ->
// one __shfl per edge (same as R13) with R14's reduced arithmetic.
template <int RELU>
__global__ __launch_bounds__(256) void k_edge(
    const u16* __restrict__ xlb, const u16* __restrict__ xrb,
    const u16* __restrict__ als,
    const int* __restrict__ row_off, const u16* __restrict__ col,
    const float* __restrict__ att, const float* __restrict__ bias,
    u16* __restrict__ hout)
{
    int gtid = blockIdx.x * 256 + threadIdx.x;
    int node = gtid >> 6;
    int lane = threadIdx.x & 63;
    int g = lane >> 4;
    int t = lane & 15;
    if (node >= N_NODES) return;

    const int d0 = t * 8;
    uint4 xru = *(const uint4*)(xrb + (size_t)node * DIM + d0);
    float2 q0 = bf2x(xru.x), q1 = bf2x(xru.y), q2 = bf2x(xru.z), q3 = bf2x(xru.w);
    float4 xr0 = make_float4(q0.x, q0.y, q1.x, q1.y);
    float4 xr1 = make_float4(q2.x, q2.y, q3.x, q3.y);
    float4 at0 = *(const float4*)(att + d0);
    float4 at1 = *(const float4*)(att + d0 + 4);
    at0.x *= 0.4f; at0.y *= 0.4f; at0.z *= 0.4f; at0.w *= 0.4f;
    at1.x *= 0.4f; at1.y *= 0.4f; at1.z *= 0.4f; at1.w *= 0.4f;

    const int beg = row_off[node];
    const int end = row_off[node + 1];
    const int n = end - beg;
    const int nreg = (n < 64) ? n : 64;

    // pack: src idx (low 16) | als bf16 (high 16) -> one shfl carries both
    u32 pkv = 0;
    if (lane < nreg) {
        u32 s = (u32)col[beg + lane];
        pkv = s | ((u32)als[s] << 16);
    }

    float acc[8];
#pragma unroll
    for (int i = 0; i < 8; ++i) acc[i] = 0.f;
    float lsum = 0.f;

    const u16* basep = xlb + d0;

#pragma unroll 1
    for (int k0 = 0; k0 < 16; k0 += 8) {
        uint4 u[8];
        u32 pks[8];
#pragma unroll
        for (int k = 0; k < 8; ++k) {
            int p = g + 4 * (k0 + k);
            int ps = (p < nreg) ? p : 0;
            u32 pj = (u32)__shfl((int)pkv, ps, 64);
            pks[k] = pj;
            if (p < nreg)
                u[k] = *(const uint4*)(basep + (size_t)(pj & 0xffff) * DIM);
        }
#pragma unroll
        for (int k = 0; k < 8; ++k) {
            int p = g + 4 * (k0 + k);
            if (p < nreg) {
                float2 p0 = bf2x(u[k].x), p1 = bf2x(u[k].y), p2 = bf2x(u[k].z), p3 = bf2x(u[k].w);
                float v0 = p0.x + xr0.x, v1 = p0.y + xr0.y, v2 = p1.x + xr0.z, v3 = p1.y + xr0.w;
                float v4 = p2.x + xr1.x, v5 = p2.y + xr1.y, v6 = p3.x + xr1.z, v7 = p3.y + xr1.w;
                float pp = at0.x * __builtin_fabsf(v0);
                pp = fmaf(at0.y, __builtin_fabsf(v1), pp);
                pp = fmaf(at0.z, __builtin_fabsf(v2), pp);
                pp = fmaf(at0.w, __builtin_fabsf(v3), pp);
                pp = fmaf(at1.x, __builtin_fabsf(v4), pp);
                pp = fmaf(at1.y, __builtin_fabsf(v5), pp);
                pp = fmaf(at1.z, __builtin_fabsf(v6), pp);
                pp = fmaf(at1.w, __builtin_fabsf(v7), pp);
                pp += __shfl_xor(pp, 1, 64);
                pp += __shfl_xor(pp, 2, 64);
                pp += __shfl_xor(pp, 4, 64);
                pp += __shfl_xor(pp, 8, 64);
                float w = __expf(pp + bf1(pks[k] >> 16));
                lsum += w;
                acc[0] = fmaf(w, p0.x, acc[0]);
                acc[1] = fmaf(w, p0.y, acc[1]);
                acc[2] = fmaf(w, p1.x, acc[2]);
                acc[3] = fmaf(w, p1.y, acc[3]);
                acc[4] = fmaf(w, p2.x, acc[4]);
                acc[5] = fmaf(w, p2.y, acc[5]);
                acc[6] = fmaf(w, p3.x, acc[6]);
                acc[7] = fmaf(w, p3.y, acc[7]);
            }
        }
    }

    // rare tail: rows longer than 64
    for (int j = beg + 64 + g; j < end; j += 4) {
        int s = (int)col[j];
        uint4 u = *(const uint4*)(basep + (size_t)s * DIM);
        float2 p0 = bf2x(u.x), p1 = bf2x(u.y), p2 = bf2x(u.z), p3 = bf2x(u.w);
        float v0 = p0.x + xr0.x, v1 = p0.y + xr0.y, v2 = p1.x + xr0.z, v3 = p1.y + xr0.w;
        float v4 = p2.x + xr1.x, v5 = p2.y + xr1.y, v6 = p3.x + xr1.z, v7 = p3.y + xr1.w;
        float pp = at0.x * __builtin_fabsf(v0);
        pp = fmaf(at0.y, __builtin_fabsf(v1), pp);
        pp = fmaf(at0.z, __builtin_fabsf(v2), pp);
        pp = fmaf(at0.w, __builtin_fabsf(v3), pp);
        pp = fmaf(at1.x, __builtin_fabsf(v4), pp);
        pp = fmaf(at1.y, __builtin_fabsf(v5), pp);
        pp = fmaf(at1.z, __builtin_fabsf(v6), pp);
        pp = fmaf(at1.w, __builtin_fabsf(v7), pp);
        pp += __shfl_xor(pp, 1, 64);
        pp += __shfl_xor(pp, 2, 64);
        pp += __shfl_xor(pp, 4, 64);
        pp += __shfl_xor(pp, 8, 64);
        float w = __expf(pp + bf1((u32)als[s]));
        lsum += w;
        acc[0] = fmaf(w, p0.x, acc[0]);
        acc[1] = fmaf(w, p0.y, acc[1]);
        acc[2] = fmaf(w, p1.x, acc[2]);
        acc[3] = fmaf(w, p1.y, acc[3]);
        acc[4] = fmaf(w, p2.x, acc[4]);
        acc[5] = fmaf(w, p2.y, acc[5]);
        acc[6] = fmaf(w, p3.x, acc[6]);
        acc[7] = fmaf(w, p3.y, acc[7]);
    }

#pragma unroll
    for (int i = 0; i < 8; ++i) {
        acc[i] += __shfl_xor(acc[i], 16, 64);
        acc[i] += __shfl_xor(acc[i], 32, 64);
    }
    lsum += __shfl_xor(lsum, 16, 64);
    lsum += __shfl_xor(lsum, 32, 64);

    if (g == 0) {
        float inv = 1.f / fmaxf(lsum, 1e-16f);
        float4 b0 = *(const float4*)(bias + d0);
        float4 b1 = *(const float4*)(bias + d0 + 4);
        float o0 = acc[0] * inv + b0.x;
        float o1 = acc[1] * inv + b0.y;
        float o2 = acc[2] * inv + b0.z;
        float o3 = acc[3] * inv + b0.w;
        float o4 = acc[4] * inv + b1.x;
        float o5 = acc[5] * inv + b1.y;
        float o6 = acc[6] * inv + b1.z;
        float o7 = acc[7] * inv + b1.w;
        if (RELU) {
            o0 = fmaxf(o0, 0.f); o1 = fmaxf(o1, 0.f);
            o2 = fmaxf(o2, 0.f); o3 = fmaxf(o3, 0.f);
            o4 = fmaxf(o4, 0.f); o5 = fmaxf(o5, 0.f);
            o6 = fmaxf(o6, 0.f); o7 = fmaxf(o7, 0.f);
        }
        uint4 o;
        o.x = pk2(o0, o1);
        o.y = pk2(o2, o3);
        o.z = pk2(o4, o5);
        o.w = pk2(o6, o7);
        *(uint4*)(hout + (size_t)node * DIM + d0) = o;
    }
}

// ---------- mean pool (bf16 h) ----------
__global__ void k_mean_part(const u16* __restrict__ hb, float* __restrict__ part) {
    int d = threadIdx.x;
    int b = blockIdx.x;
    int n0 = b * 200;
    float s = 0.f;
    for (int i = 0; i < 200; ++i) {
        union { u32 i; float f; } v;
        v.i = (u32)hb[(size_t)(n0 + i) * DIM + d] << 16;
        s += v.f;
    }
    part[b * DIM + d] = s;
}

__global__ void k_mean_final(const float* __restrict__ part, float* __restrict__ out) {
    int d = threadIdx.x;
    float s = 0.f;
    for (int b = 0; b < 250; ++b) s += part[b * DIM + d];
    out[d] = s * (1.f / (float)N_NODES);
}

// ---------- launch ----------
extern "C" void kernel_launch(void* const* d_in, const int* in_sizes, int n_in,
                              void* d_out, int out_size, void* d_ws, size_t ws_size,
                              hipStream_t stream) {
    int ix, iei, iWl, ibl, iWr, ibr, iatt, ibias;
    if (in_sizes[0] == N_NODES * DIM) {
        ix = 0; iei = 1; iWl = 2; ibl = 3; iWr = 4; ibr = 5; iatt = 6; ibias = 7;
    } else {
        iWl = 0; iWr = 1; iatt = 2; ibias = 3; ibl = 4; ibr = 5; iei = 6; ix = 7;
    }
    const float* x    = (const float*)d_in[ix];
    const void*  ei   = d_in[iei];
    const float* Wl   = (const float*)d_in[iWl];
    const float* bl   = (const float*)d_in[ibl];
    const float* Wr   = (const float*)d_in[iWr];
    const float* br   = (const float*)d_in[ibr];
    const float* att  = (const float*)d_in[iatt];
    const float* bias = (const float*)d_in[ibias];
    float* out = (float*)d_out;

    char* w = (char*)d_ws;
    float* part = (float*)w;      w += (size_t)256 * DIM * 4;
    u16* als = (u16*)w;           w += (size_t)(N_NODES + 32) * 2;
    uint4* Wtg = (uint4*)w;       w += (size_t)N_LAYERS * 4096 * 16;
    u16* xb  = (u16*)w;           w += (size_t)N_NODES * DIM * 2;
    u16* hb  = (u16*)w;           w += (size_t)N_NODES * DIM * 2;
    u16* xlb = (u16*)w;           w += (size_t)N_NODES * DIM * 2;
    u16* xrb = (u16*)w;           w += (size_t)N_NODES * DIM * 2;
    int* row_off = (int*)w;       w += (size_t)(N_NODES + 4) * 4;
    int* flags = (int*)w;         w += 64;
    int* bcnt = (int*)w;          w += (size_t)(NBKT + 4) * 4;
    int* btot = (int*)w;          w += (size_t)(NBKT + 4) * 4;
    int* boff = (int*)w;          w += (size_t)(NBKT + 4) * 4;
    u32* bpk = (u32*)w;           w += (size_t)NBKT * BCAP_A * 4;
    u16* col = (u16*)w;           w += (size_t)(N_EDGES + N_NODES + 64) * 2;

    k_probe<<<1, 256, 0, stream>>>((const int*)ei, flags, bcnt);
    k_cvt_x<<<(N_NODES * DIM / 2 + 255) / 256, 256, 0, stream>>>(x, xb);
    k_cvt_w<<<(N_LAYERS * 4096 + 255) / 256, 256, 0, stream>>>(Wl, Wr, Wtg);
    k_part<<<PBLK, 1024, 0, stream>>>(ei, flags, bcnt, bpk);
    k_deg<<<NBKT, 256, 0, stream>>>(bpk, bcnt, ei, flags, row_off, btot);
    k_bscan<<<1, 256, 0, stream>>>(btot, boff, row_off);
    k_scat<<<NBKT, 256, 0, stream>>>(bpk, bcnt, row_off, boff, btot, col, ei, flags);

    const int mm_grid = (N_NODES + 63) / 64;
    const int edge_grid = (N_NODES * 64 + 255) / 256;

    for (int layer = 0; layer < N_LAYERS; ++layer) {
        const uint4* Wp = Wtg + (size_t)layer * 4096;
        const float* blp = bl + (size_t)layer * DIM;
        const float* brp = br + (size_t)layer * DIM;
        const float* ap  = att + (size_t)layer * DIM;
        const float* bp  = bias + (size_t)layer * DIM;

        const u16* hin = (layer == 0) ? xb : hb;
        k_mm<<<mm_grid, 256, 0, stream>>>(hin, Wp, blp, brp, ap, xlb, xrb, als);

        if (layer < N_LAYERS - 1)
            k_edge<1><<<edge_grid, 256, 0, stream>>>(xlb, xrb, als, row_off, col, ap, bp, hb);
        else
            k_edge<0><<<edge_grid, 256, 0, stream>>>(xlb, xrb, als, row_off, col, ap, bp, hb);
    }

    k_mean_part<<<250, 128, 0, stream>>>(hb, part);
    k_mean_final<<<1, 128, 0, stream>>>(part, out);
}

// Round 16
// 695.385 us; speedup vs baseline: 1.1086x; 1.0281x over previous
//
#include <hip/hip_runtime.h>
#include <hip/hip_bf16.h>

#define N_NODES 50000
#define N_EDGES 1600000
#define DIM 128
#define N_LAYERS 5
#define NEG 0.2f

#define NBKT 196          // dst >> 8
#define BCAP_A 9472       // arena cap per bucket (mean 8163)
#define PBLK 98           // partition blocks
#define EPB 16384         // edges per partition block
#define SEGCAP 12288      // k_scat staging entries (u16)

typedef unsigned short u16;
typedef unsigned char u8;
typedef unsigned int u32;
using short8 = __attribute__((ext_vector_type(8))) short;
using f32x4  = __attribute__((ext_vector_type(4))) float;

union FragU { uint4 u; short8 s; };

// ---------- helpers ----------
__device__ __forceinline__ float2 bf2x(u32 u) {
    union { u32 i; float f; } lo, hi;
    lo.i = u << 16;
    hi.i = u & 0xffff0000u;
    return make_float2(lo.f, hi.f);
}
__device__ __forceinline__ u16 f2bf(float f) {   // RNE
    union { float f; u32 u; } v; v.f = f;
    u32 r = v.u + 0x7fffu + ((v.u >> 16) & 1u);
    return (u16)(r >> 16);
}
__device__ __forceinline__ u32 pk2(float a, float b) {
    return (u32)f2bf(a) | ((u32)f2bf(b) << 16);
}
__device__ __forceinline__ int clampi(int v) {
    v = (v < 0) ? 0 : v;
    return (v >= N_NODES) ? (N_NODES - 1) : v;
}

// ---------- probe + bcnt zero ----------
__global__ void k_probe(const int* __restrict__ ei32, int* __restrict__ flags,
                        int* __restrict__ bcnt) {
    __shared__ int cnt;
    int t = threadIdx.x;
    if (t == 0) cnt = 0;
    __syncthreads();
    if (ei32[2 * t + 1] == 0) atomicAdd(&cnt, 1);
    if (t < NBKT) bcnt[t] = 0;
    __syncthreads();
    if (t == 0) flags[0] = (cnt >= 255) ? 1 : 0;
}

__device__ __forceinline__ int ldidx(const void* ei, long long i, int m64) {
    int v = m64 ? (int)(((const long long*)ei)[i]) : ((const int*)ei)[i];
    return clampi(v);
}

// ---------- conversions ----------
__global__ void k_cvt_x(const float* __restrict__ x, u16* __restrict__ xb) {
    int i = blockIdx.x * 256 + threadIdx.x;
    float2 v = *(const float2*)(x + (size_t)i * 2);
    ((u32*)xb)[i] = pk2(v.x, v.y);
}

__global__ void k_cvt_w(const float* __restrict__ Wl, const float* __restrict__ Wr,
                        uint4* __restrict__ Wtg) {
    int id = blockIdx.x * 256 + threadIdx.x;
    if (id >= N_LAYERS * 16 * 256) return;
    int l = id >> 12;
    int rem = id & 4095;
    int kc = rem >> 8;
    int n = rem & 255;
    const float* W = (n < 128) ? (Wl + (size_t)l * DIM * DIM + n)
                               : (Wr + (size_t)l * DIM * DIM + (n - 128));
    u16 c[8];
#pragma unroll
    for (int j = 0; j < 8; ++j) c[j] = f2bf(W[(size_t)(kc * 8 + j) * DIM]);
    uint4 o;
    o.x = (u32)c[0] | ((u32)c[1] << 16);
    o.y = (u32)c[2] | ((u32)c[3] << 16);
    o.z = (u32)c[4] | ((u32)c[5] << 16);
    o.w = (u32)c[6] | ((u32)c[7] << 16);
    Wtg[(size_t)l * 4096 + n * 16 + (kc ^ (n & 15))] = o;
}

// ---------- CSR build: LDS-staged bucket partition ----------
__global__ __launch_bounds__(1024) void k_part(
    const void* __restrict__ ei, const int* __restrict__ flags,
    int* __restrict__ bcnt, u32* __restrict__ bpk)
{
    __shared__ u32 ebuf[EPB];        // 64 KB
    __shared__ u8  bkb[EPB];         // 16 KB
    __shared__ int lh[NBKT];
    __shared__ int lb[NBKT + 1];
    __shared__ int gst[NBKT];
    __shared__ int sc[256];

    const int tid = threadIdx.x;
    const int m64 = flags[0];
    const long long e0 = (long long)blockIdx.x * EPB;

    for (int i = tid; i < NBKT; i += 1024) lh[i] = 0;
    __syncthreads();

    u32 pay[16];
    u32 meta[16];
    int nv = 0;
#pragma unroll
    for (int i = 0; i < 16; ++i) {
        long long e = e0 + i * 1024 + tid;
        if (e < N_EDGES) {
            int s = ldidx(ei, e, m64);
            int d = ldidx(ei, (long long)N_EDGES + e, m64);
            int b = d >> 8;
            int rank = atomicAdd(&lh[b], 1);
            pay[i] = (u32)s | ((u32)(d & 255) << 16);
            meta[i] = (u32)b | ((u32)rank << 8);
            nv = i + 1;
        }
    }
    __syncthreads();

    if (tid < 256) sc[tid] = (tid < NBKT) ? lh[tid] : 0;
    __syncthreads();
    for (int off = 1; off < 256; off <<= 1) {
        int v = 0;
        if (tid < 256 && tid >= off) v = sc[tid - off];
        __syncthreads();
        if (tid < 256) sc[tid] += v;
        __syncthreads();
    }
    if (tid < NBKT) lb[tid] = sc[tid] - lh[tid];
    if (tid == 0) lb[NBKT] = 0;
    if (tid < NBKT) gst[tid] = atomicAdd(&bcnt[tid], lh[tid]);
    __syncthreads();

#pragma unroll
    for (int i = 0; i < 16; ++i) {
        if (i < nv) {
            int b = (int)(meta[i] & 255);
            int rank = (int)(meta[i] >> 8);
            int p = lb[b] + rank;
            ebuf[p] = pay[i];
            bkb[p] = (u8)b;
        }
    }
    __syncthreads();

    int total = (e0 + EPB <= N_EDGES) ? EPB : (int)(N_EDGES - e0);
    for (int i = tid; i < total; i += 1024) {
        int b = (int)bkb[i];
        int off = gst[b] + (i - lb[b]);
        if (off < BCAP_A)
            bpk[(size_t)b * BCAP_A + off] = ebuf[i];
    }
}

// per-bucket degree + LOCAL row_off scan + bucket total
__global__ __launch_bounds__(256) void k_deg(
    const u32* __restrict__ bpk, const int* __restrict__ bcnt,
    const void* __restrict__ ei, const int* __restrict__ flags,
    int* __restrict__ row_off, int* __restrict__ btot)
{
    __shared__ int dh[256];
    __shared__ int sc[256];
    int b = blockIdx.x;
    int tid = threadIdx.x;
    dh[tid] = 0;
    __syncthreads();
    int cnt = bcnt[b];
    if (cnt <= BCAP_A) {
        for (int i = tid; i < cnt; i += 256)
            atomicAdd(&dh[(bpk[(size_t)b * BCAP_A + i] >> 16) & 255], 1);
    } else {
        int m64 = flags[0];
        for (long long e = tid; e < N_EDGES; e += 256) {
            int d = ldidx(ei, (long long)N_EDGES + e, m64);
            if ((d >> 8) == b) atomicAdd(&dh[d & 255], 1);
        }
    }
    __syncthreads();
    int d = b * 256 + tid;
    int v = (d < N_NODES) ? (dh[tid] + 1) : 0;    // +1 self loop
    sc[tid] = v;
    __syncthreads();
    for (int off = 1; off < 256; off <<= 1) {
        int t = (tid >= off) ? sc[tid - off] : 0;
        __syncthreads();
        sc[tid] += t;
        __syncthreads();
    }
    if (d < N_NODES) row_off[d] = sc[tid] - v;    // local exclusive
    if (tid == 255) btot[b] = sc[255];
}

__global__ void k_bscan(const int* __restrict__ btot, int* __restrict__ boff,
                        int* __restrict__ row_off) {
    __shared__ int sc[256];
    int tid = threadIdx.x;
    int v = (tid < NBKT) ? btot[tid] : 0;
    sc[tid] = v;
    __syncthreads();
    for (int off = 1; off < 256; off <<= 1) {
        int t = (tid >= off) ? sc[tid - off] : 0;
        __syncthreads();
        sc[tid] += t;
        __syncthreads();
    }
    if (tid < NBKT) boff[tid] = sc[tid] - v;
    if (tid == NBKT - 1) row_off[N_NODES] = sc[tid];
}

__global__ __launch_bounds__(256) void k_scat(
    const u32* __restrict__ bpk, const int* __restrict__ bcnt,
    int* __restrict__ row_off, const int* __restrict__ boff,
    const int* __restrict__ btot, u16* __restrict__ col,
    const void* __restrict__ ei, const int* __restrict__ flags)
{
    __shared__ u16 stage[SEGCAP];    // 24 KB
    __shared__ int cur[256];
    int b = blockIdx.x;
    int tid = threadIdx.x;
    int d_lo = b * 256;
    int d_hi = d_lo + 256; if (d_hi > N_NODES) d_hi = N_NODES;
    int base0 = boff[b];
    int seglen = btot[b];
    if (seglen > SEGCAP) seglen = SEGCAP;

    int d = d_lo + tid;
    int rloc = 0;
    if (d < d_hi) {
        rloc = row_off[d];
        if (rloc < SEGCAP) stage[rloc] = (u16)d;
        cur[tid] = rloc + 1;
    }
    __syncthreads();

    int cnt = bcnt[b];
    if (cnt <= BCAP_A) {
        for (int i = tid; i < cnt; i += 256) {
            u32 p = bpk[(size_t)b * BCAP_A + i];
            int pos = atomicAdd(&cur[(p >> 16) & 255], 1);
            if (pos < SEGCAP) stage[pos] = (u16)(p & 0xffff);
        }
    } else {
        int m64 = flags[0];
        for (long long e = tid; e < N_EDGES; e += 256) {
            int dd = ldidx(ei, (long long)N_EDGES + e, m64);
            if ((dd >> 8) == b) {
                int s = ldidx(ei, e, m64);
                int pos = atomicAdd(&cur[dd & 255], 1);
                if (pos < SEGCAP) stage[pos] = (u16)s;
            }
        }
    }
    __syncthreads();
    for (int i = tid; i < seglen; i += 256)
        col[base0 + i] = stage[i];
    if (d < d_hi) row_off[d] = base0 + rloc;
}

// ---------- MFMA GEMM: [xl|xr] = h_bf16 @ [Wl|Wr] + [bl|br]; both out bf16 ----------
__global__ __launch_bounds__(256) void k_mm(
    const u16* __restrict__ hb,
    const uint4* __restrict__ Wtg,
    const float* __restrict__ bl, const float* __restrict__ br,
    u16* __restrict__ xlb,
    u16* __restrict__ xrb)
{
    __shared__ uint4 wsh[4096];          // 64 KB
    const int tid = threadIdx.x;
#pragma unroll
    for (int i = 0; i < 16; ++i) wsh[tid + i * 256] = Wtg[tid + i * 256];

    const int wave = tid >> 6, lane = tid & 63;
    const int q = lane >> 4, nn = lane & 15;
    const int mA = blockIdx.x * 64 + wave * 16 + nn;

    FragU afr[4];
    const uint4 az = make_uint4(0, 0, 0, 0);
#pragma unroll
    for (int s = 0; s < 4; ++s)
        afr[s].u = (mA < N_NODES)
                 ? *(const uint4*)(hb + (size_t)mA * DIM + s * 32 + q * 8)
                 : az;
    __syncthreads();

    f32x4 acc[16];
#pragma unroll
    for (int i = 0; i < 16; ++i) acc[i] = (f32x4){0.f, 0.f, 0.f, 0.f};

#pragma unroll
    for (int s = 0; s < 4; ++s) {
#pragma unroll
        for (int nt = 0; nt < 16; ++nt) {
            int n = nt * 16 + nn;
            int kc = s * 4 + q;
            FragU b;
            b.u = wsh[n * 16 + (kc ^ (n & 15))];
            acc[nt] = __builtin_amdgcn_mfma_f32_16x16x32_bf16(afr[s].s, b.s, acc[nt], 0, 0, 0);
        }
    }

    const int mBase = blockIdx.x * 64 + wave * 16 + q * 4;
#pragma unroll
    for (int nt = 0; nt < 16; ++nt) {
        int n = nt * 16 + nn;
        bool isL = (n < 128);
        float bv = isL ? bl[n] : br[n - 128];
#pragma unroll
        for (int r = 0; r < 4; ++r) {
            int m = mBase + r;
            if (m < N_NODES) {
                float v = acc[nt][r] + bv;
                if (isL) xlb[(size_t)m * DIM + n] = f2bf(v);
                else     xrb[(size_t)m * DIM + (n - 128)] = f2bf(v);
            }
        }
    }
}

// ---------- fused edge phase: R13 math in strict float2 (VOP3P-packable) form ----------
template <int RELU>
__global__ __launch_bounds__(256) void k_edge(
    const u16* __restrict__ xlb, const u16* __restrict__ xrb,
    const int* __restrict__ row_off, const u16* __restrict__ col,
    const float* __restrict__ att, const float* __restrict__ bias,
    u16* __restrict__ hout)
{
    int gtid = blockIdx.x * 256 + threadIdx.x;
    int node = gtid >> 6;
    int lane = threadIdx.x & 63;
    int g = lane >> 4;
    int t = lane & 15;
    if (node >= N_NODES) return;

    const int d0 = t * 8;
    uint4 xru = *(const uint4*)(xrb + (size_t)node * DIM + d0);
    float2 xr01 = bf2x(xru.x), xr23 = bf2x(xru.y), xr45 = bf2x(xru.z), xr67 = bf2x(xru.w);
    float2 at01 = *(const float2*)(att + d0);
    float2 at23 = *(const float2*)(att + d0 + 2);
    float2 at45 = *(const float2*)(att + d0 + 4);
    float2 at67 = *(const float2*)(att + d0 + 6);

    const int beg = row_off[node];
    const int end = row_off[node + 1];
    const int n = end - beg;
    const int nreg = (n < 64) ? n : 64;

    int idx = (lane < nreg) ? (int)col[beg + lane] : 0;

    float2 ac01 = make_float2(0.f, 0.f), ac23 = make_float2(0.f, 0.f);
    float2 ac45 = make_float2(0.f, 0.f), ac67 = make_float2(0.f, 0.f);
    float lsum = 0.f;
    const u16* basep = xlb + d0;

#pragma unroll 1
    for (int k0 = 0; k0 < 16; k0 += 8) {
        uint4 u[8];
#pragma unroll
        for (int k = 0; k < 8; ++k) {
            int p = g + 4 * (k0 + k);
            int ps = (p < nreg) ? p : 0;
            int s = __shfl(idx, ps, 64);
            if (p < nreg)
                u[k] = *(const uint4*)(basep + (size_t)s * DIM);
        }
#pragma unroll
        for (int k = 0; k < 8; ++k) {
            int p = g + 4 * (k0 + k);
            if (p < nreg) {
                float2 x01 = bf2x(u[k].x), x23 = bf2x(u[k].y);
                float2 x45 = bf2x(u[k].z), x67 = bf2x(u[k].w);
                // z = xl + xr (pairs)
                float2 z01 = make_float2(x01.x + xr01.x, x01.y + xr01.y);
                float2 z23 = make_float2(x23.x + xr23.x, x23.y + xr23.y);
                float2 z45 = make_float2(x45.x + xr45.x, x45.y + xr45.y);
                float2 z67 = make_float2(x67.x + xr67.x, x67.y + xr67.y);
                // lrelu = max(z, 0.2z) (pairs: pk_mul + pk_max)
                z01.x = fmaxf(z01.x, NEG * z01.x); z01.y = fmaxf(z01.y, NEG * z01.y);
                z23.x = fmaxf(z23.x, NEG * z23.x); z23.y = fmaxf(z23.y, NEG * z23.y);
                z45.x = fmaxf(z45.x, NEG * z45.x); z45.y = fmaxf(z45.y, NEG * z45.y);
                z67.x = fmaxf(z67.x, NEG * z67.x); z67.y = fmaxf(z67.y, NEG * z67.y);
                // score (pairs: pk_fma), final horizontal add
                float2 pp2;
                pp2.x = at01.x * z01.x;            pp2.y = at01.y * z01.y;
                pp2.x = fmaf(at23.x, z23.x, pp2.x); pp2.y = fmaf(at23.y, z23.y, pp2.y);
                pp2.x = fmaf(at45.x, z45.x, pp2.x); pp2.y = fmaf(at45.y, z45.y, pp2.y);
                pp2.x = fmaf(at67.x, z67.x, pp2.x); pp2.y = fmaf(at67.y, z67.y, pp2.y);
                float pp = pp2.x + pp2.y;
                pp += __shfl_xor(pp, 1, 64);
                pp += __shfl_xor(pp, 2, 64);
                pp += __shfl_xor(pp, 4, 64);
                pp += __shfl_xor(pp, 8, 64);
                float w = __expf(pp);
                lsum += w;
                ac01.x = fmaf(w, x01.x, ac01.x); ac01.y = fmaf(w, x01.y, ac01.y);
                ac23.x = fmaf(w, x23.x, ac23.x); ac23.y = fmaf(w, x23.y, ac23.y);
                ac45.x = fmaf(w, x45.x, ac45.x); ac45.y = fmaf(w, x45.y, ac45.y);
                ac67.x = fmaf(w, x67.x, ac67.x); ac67.y = fmaf(w, x67.y, ac67.y);
            }
        }
    }

    // rare tail: rows longer than 64
    for (int j = beg + 64 + g; j < end; j += 4) {
        int s = (int)col[j];
        uint4 u = *(const uint4*)(basep + (size_t)s * DIM);
        float2 x01 = bf2x(u.x), x23 = bf2x(u.y), x45 = bf2x(u.z), x67 = bf2x(u.w);
        float2 z01 = make_float2(x01.x + xr01.x, x01.y + xr01.y);
        float2 z23 = make_float2(x23.x + xr23.x, x23.y + xr23.y);
        float2 z45 = make_float2(x45.x + xr45.x, x45.y + xr45.y);
        float2 z67 = make_float2(x67.x + xr67.x, x67.y + xr67.y);
        z01.x = fmaxf(z01.x, NEG * z01.x); z01.y = fmaxf(z01.y, NEG * z01.y);
        z23.x = fmaxf(z23.x, NEG * z23.x); z23.y = fmaxf(z23.y, NEG * z23.y);
        z45.x = fmaxf(z45.x, NEG * z45.x); z45.y = fmaxf(z45.y, NEG * z45.y);
        z67.x = fmaxf(z67.x, NEG * z67.x); z67.y = fmaxf(z67.y, NEG * z67.y);
        float2 pp2;
        pp2.x = at01.x * z01.x;            pp2.y = at01.y * z01.y;
        pp2.x = fmaf(at23.x, z23.x, pp2.x); pp2.y = fmaf(at23.y, z23.y, pp2.y);
        pp2.x = fmaf(at45.x, z45.x, pp2.x); pp2.y = fmaf(at45.y, z45.y, pp2.y);
        pp2.x = fmaf(at67.x, z67.x, pp2.x); pp2.y = fmaf(at67.y, z67.y, pp2.y);
        float pp = pp2.x + pp2.y;
        pp += __shfl_xor(pp, 1, 64);
        pp += __shfl_xor(pp, 2, 64);
        pp += __shfl_xor(pp, 4, 64);
        pp += __shfl_xor(pp, 8, 64);
        float w = __expf(pp);
        lsum += w;
        ac01.x = fmaf(w, x01.x, ac01.x); ac01.y = fmaf(w, x01.y, ac01.y);
        ac23.x = fmaf(w, x23.x, ac23.x); ac23.y = fmaf(w, x23.y, ac23.y);
        ac45.x = fmaf(w, x45.x, ac45.x); ac45.y = fmaf(w, x45.y, ac45.y);
        ac67.x = fmaf(w, x67.x, ac67.x); ac67.y = fmaf(w, x67.y, ac67.y);
    }

    // merge the 4 groups
    float accv[8] = {ac01.x, ac01.y, ac23.x, ac23.y, ac45.x, ac45.y, ac67.x, ac67.y};
#pragma unroll
    for (int i = 0; i < 8; ++i) {
        accv[i] += __shfl_xor(accv[i], 16, 64);
        accv[i] += __shfl_xor(accv[i], 32, 64);
    }
    lsum += __shfl_xor(lsum, 16, 64);
    lsum += __shfl_xor(lsum, 32, 64);

    if (g == 0) {
        float inv = 1.f / fmaxf(lsum, 1e-16f);
        float4 b0 = *(const float4*)(bias + d0);
        float4 b1 = *(const float4*)(bias + d0 + 4);
        float o0 = accv[0] * inv + b0.x;
        float o1 = accv[1] * inv + b0.y;
        float o2 = accv[2] * inv + b0.z;
        float o3 = accv[3] * inv + b0.w;
        float o4 = accv[4] * inv + b1.x;
        float o5 = accv[5] * inv + b1.y;
        float o6 = accv[6] * inv + b1.z;
        float o7 = accv[7] * inv + b1.w;
        if (RELU) {
            o0 = fmaxf(o0, 0.f); o1 = fmaxf(o1, 0.f);
            o2 = fmaxf(o2, 0.f); o3 = fmaxf(o3, 0.f);
            o4 = fmaxf(o4, 0.f); o5 = fmaxf(o5, 0.f);
            o6 = fmaxf(o6, 0.f); o7 = fmaxf(o7, 0.f);
        }
        uint4 o;
        o.x = pk2(o0, o1);
        o.y = pk2(o2, o3);
        o.z = pk2(o4, o5);
        o.w = pk2(o6, o7);
        *(uint4*)(hout + (size_t)node * DIM + d0) = o;
    }
}

// ---------- mean pool (bf16 h) ----------
__global__ void k_mean_part(const u16* __restrict__ hb, float* __restrict__ part) {
    int d = threadIdx.x;
    int b = blockIdx.x;
    int n0 = b * 200;
    float s = 0.f;
    for (int i = 0; i < 200; ++i) {
        union { u32 i; float f; } v;
        v.i = (u32)hb[(size_t)(n0 + i) * DIM + d] << 16;
        s += v.f;
    }
    part[b * DIM + d] = s;
}

__global__ void k_mean_final(const float* __restrict__ part, float* __restrict__ out) {
    int d = threadIdx.x;
    float s = 0.f;
    for (int b = 0; b < 250; ++b) s += part[b * DIM + d];
    out[d] = s * (1.f / (float)N_NODES);
}

// ---------- launch ----------
extern "C" void kernel_launch(void* const* d_in, const int* in_sizes, int n_in,
                              void* d_out, int out_size, void* d_ws, size_t ws_size,
                              hipStream_t stream) {
    int ix, iei, iWl, ibl, iWr, ibr, iatt, ibias;
    if (in_sizes[0] == N_NODES * DIM) {
        ix = 0; iei = 1; iWl = 2; ibl = 3; iWr = 4; ibr = 5; iatt = 6; ibias = 7;
    } else {
        iWl = 0; iWr = 1; iatt = 2; ibias = 3; ibl = 4; ibr = 5; iei = 6; ix = 7;
    }
    const float* x    = (const float*)d_in[ix];
    const void*  ei   = d_in[iei];
    const float* Wl   = (const float*)d_in[iWl];
    const float* bl   = (const float*)d_in[ibl];
    const float* Wr   = (const float*)d_in[iWr];
    const float* br   = (const float*)d_in[ibr];
    const float* att  = (const float*)d_in[iatt];
    const float* bias = (const float*)d_in[ibias];
    float* out = (float*)d_out;

    char* w = (char*)d_ws;
    float* part = (float*)w;      w += (size_t)256 * DIM * 4;
    uint4* Wtg = (uint4*)w;       w += (size_t)N_LAYERS * 4096 * 16;
    u16* xb  = (u16*)w;           w += (size_t)N_NODES * DIM * 2;
    u16* hb  = (u16*)w;           w += (size_t)N_NODES * DIM * 2;
    u16* xlb = (u16*)w;           w += (size_t)N_NODES * DIM * 2;
    u16* xrb = (u16*)w;           w += (size_t)N_NODES * DIM * 2;
    int* row_off = (int*)w;       w += (size_t)(N_NODES + 4) * 4;
    int* flags = (int*)w;         w += 64;
    int* bcnt = (int*)w;          w += (size_t)(NBKT + 4) * 4;
    int* btot = (int*)w;          w += (size_t)(NBKT + 4) * 4;
    int* boff = (int*)w;          w += (size_t)(NBKT + 4) * 4;
    u32* bpk = (u32*)w;           w += (size_t)NBKT * BCAP_A * 4;
    u16* col = (u16*)w;           w += (size_t)(N_EDGES + N_NODES + 64) * 2;

    k_probe<<<1, 256, 0, stream>>>((const int*)ei, flags, bcnt);
    k_cvt_x<<<(N_NODES * DIM / 2 + 255) / 256, 256, 0, stream>>>(x, xb);
    k_cvt_w<<<(N_LAYERS * 4096 + 255) / 256, 256, 0, stream>>>(Wl, Wr, Wtg);
    k_part<<<PBLK, 1024, 0, stream>>>(ei, flags, bcnt, bpk);
    k_deg<<<NBKT, 256, 0, stream>>>(bpk, bcnt, ei, flags, row_off, btot);
    k_bscan<<<1, 256, 0, stream>>>(btot, boff, row_off);
    k_scat<<<NBKT, 256, 0, stream>>>(bpk, bcnt, row_off, boff, btot, col, ei, flags);

    const int mm_grid = (N_NODES + 63) / 64;
    const int edge_grid = (N_NODES * 64 + 255) / 256;

    for (int layer = 0; layer < N_LAYERS; ++layer) {
        const uint4* Wp = Wtg + (size_t)layer * 4096;
        const float* blp = bl + (size_t)layer * DIM;
        const float* brp = br + (size_t)layer * DIM;
        const float* ap  = att + (size_t)layer * DIM;
        const float* bp  = bias + (size_t)layer * DIM;

        const u16* hin = (layer == 0) ? xb : hb;
        k_mm<<<mm_grid, 256, 0, stream>>>(hin, Wp, blp, brp, xlb, xrb);

        if (layer < N_LAYERS - 1)
            k_edge<1><<<edge_grid, 256, 0, stream>>>(xlb, xrb, row_off, col, ap, bp, hb);
        else
            k_edge<0><<<edge_grid, 256, 0, stream>>>(xlb, xrb, row_off, col, ap, bp, hb);
    }

    k_mean_part<<<250, 128, 0, stream>>>(hb, part);
    k_mean_final<<<1, 128, 0, stream>>>(part, out);
}